// Round 2
// baseline (355.497 us; speedup 1.0000x reference)
//
#include <hip/hip_runtime.h>
#include <hip/hip_bf16.h>

typedef __attribute__((ext_vector_type(8))) __bf16 bf16x8;
typedef __attribute__((ext_vector_type(8))) unsigned short u16x8;
typedef __attribute__((ext_vector_type(4))) float f32x4;

#define MFMA_BF16(a,b,c) __builtin_amdgcn_mfma_f32_16x16x32_bf16((a),(b),(c),0,0,0)

#define ASCALE 0.125f
#define SEQT 512
#define NB 32
#define BT 16384  // NB*SEQT

#define GLD_LDS16(g, l) __builtin_amdgcn_global_load_lds( \
    (__attribute__((address_space(1))) void*)(g), \
    (__attribute__((address_space(3))) void*)(l), 16, 0, 0)

__device__ __forceinline__ unsigned short f2bf(float f) {
    unsigned int u = __float_as_uint(f);
    u += 0x7fffu + ((u >> 16) & 1u);
    return (unsigned short)(u >> 16);
}
__device__ __forceinline__ float bf2f(unsigned short h) {
    return __uint_as_float(((unsigned int)h) << 16);
}

// ---------- cast x (fp32 -> bf16), 4 elems/thread ----------
__global__ __launch_bounds__(256) void cast_x_kernel(const float* __restrict__ x,
                                                     unsigned short* __restrict__ xb, int n) {
    int i = (blockIdx.x * 256 + threadIdx.x) * 4;
    if (i < n) {
        float4 v = *(const float4*)(x + i);
        ushort4 o;
        o.x = f2bf(v.x); o.y = f2bf(v.y); o.z = f2bf(v.z); o.w = f2bf(v.w);
        *(ushort4*)(xb + i) = o;
    }
}

// ---------- weight convert + transpose: src (K x 256) fp32 -> dst (256 x K) bf16 ----------
__global__ __launch_bounds__(256) void wconv_kernel(const float* __restrict__ src,
                                                    unsigned short* __restrict__ dst, int K) {
    int k = blockIdx.x, n = threadIdx.x;
    dst[(size_t)n * K + k] = f2bf(src[(size_t)k * 256 + n]);
}

// ---------- bias concat (5 x 256) ----------
__global__ __launch_bounds__(256) void biascat_kernel(const float* b0, const float* b1,
                                                      const float* b2, const float* b3,
                                                      const float* b4, float* out) {
    int j = blockIdx.x, d = threadIdx.x;
    const float* src = (j == 0) ? b0 : (j == 1) ? b1 : (j == 2) ? b2 : (j == 3) ? b3 : b4;
    out[j * 256 + d] = src[d];
}

// ---------- GEMM 128x128 tile, 4 waves, 4x4 frags, BK=32, global_load_lds staging ----------
// C[m][n] = sum_k A[m][k] * Bt[n][k] + bias. mode 0: bf16 out; 1: f32 out (+resid).
__global__ __launch_bounds__(256)
void gemm128(const unsigned short* __restrict__ A, const unsigned short* __restrict__ Bt,
             const float* __restrict__ bias, int K,
             void* __restrict__ out, int ldc, int mode, int do_relu, int bias_row,
             const float* __restrict__ resid) {
    __shared__ __align__(16) unsigned short As[128 * 32];
    __shared__ __align__(16) unsigned short Bs[128 * 32];
    const int tid = threadIdx.x;
    const int w = tid >> 6, l = tid & 63, g = l >> 4, rl = l & 15;
    const int wm = w >> 1, wn = w & 1;
    const int m0 = blockIdx.x * 128, n0 = blockIdx.y * 128;
    const int srow = l >> 2, scol = (l & 3) * 8;

    f32x4 acc[4][4];
    #pragma unroll
    for (int m = 0; m < 4; ++m)
        #pragma unroll
        for (int n = 0; n < 4; ++n) acc[m][n] = (f32x4){0.f, 0.f, 0.f, 0.f};

    for (int k0 = 0; k0 < K; k0 += 32) {
        #pragma unroll
        for (int j = 0; j < 2; ++j) {
            int c = w * 2 + j;
            const unsigned short* ga = A  + (size_t)(m0 + c * 16 + srow) * K + k0 + scol;
            const unsigned short* gb = Bt + (size_t)(n0 + c * 16 + srow) * K + k0 + scol;
            GLD_LDS16(ga, As + c * 512);
            GLD_LDS16(gb, Bs + c * 512);
        }
        __syncthreads();
        bf16x8 af[4], bfr[4];
        #pragma unroll
        for (int m = 0; m < 4; ++m) af[m]  = *(const bf16x8*)&As[(wm * 64 + m * 16 + rl) * 32 + g * 8];
        #pragma unroll
        for (int n = 0; n < 4; ++n) bfr[n] = *(const bf16x8*)&Bs[(wn * 64 + n * 16 + rl) * 32 + g * 8];
        #pragma unroll
        for (int m = 0; m < 4; ++m)
            #pragma unroll
            for (int n = 0; n < 4; ++n)
                acc[m][n] = MFMA_BF16(af[m], bfr[n], acc[m][n]);
        __syncthreads();
    }

    const int crow0 = m0 + wm * 64, ccol0 = n0 + wn * 64;
    #pragma unroll
    for (int m = 0; m < 4; ++m) {
        #pragma unroll
        for (int n = 0; n < 4; ++n) {
            #pragma unroll
            for (int r = 0; r < 4; ++r) {
                int row = crow0 + m * 16 + g * 4 + r;
                int col = ccol0 + n * 16 + rl;
                float v = acc[m][n][r] + (bias_row ? bias[row] : bias[col]);
                if (do_relu) v = fmaxf(v, 0.f);
                if (mode == 0) {
                    ((unsigned short*)out)[(size_t)row * ldc + col] = f2bf(v);
                } else {
                    float res = resid ? resid[(size_t)row * ldc + col] : 0.f;
                    ((float*)out)[(size_t)row * ldc + col] = v + res;
                }
            }
        }
    }
}

// ---------- global attention v2: no online-max (logits bounded), V pre-transposed ----------
// q at proj col 0, k at proj col 256 (row stride 1280); vT is [256][16384].
__global__ __launch_bounds__(256)
void attn_global2(const unsigned short* __restrict__ proj, const unsigned short* __restrict__ vT,
                  const float* __restrict__ rpb, unsigned short* __restrict__ gout) {
    __shared__ __align__(16) unsigned short Ks[64][72];
    __shared__ __align__(16) unsigned short Vs[64][72];   // Vs[d_local][s_local]
    __shared__ __align__(16) unsigned short Ps[64][72];
    __shared__ float rb_s[127];

    const int tid = threadIdx.x;
    const int w = tid >> 6, l = tid & 63, g = l >> 4, rl = l & 15;
    const int bh = blockIdx.y, b = bh >> 2, h = bh & 3;
    const int t0 = blockIdx.x * 64;

    // Q fragment: rows t0 + w*16 + rl, k = d in head
    bf16x8 qf[2];
    #pragma unroll
    for (int kk = 0; kk < 2; ++kk)
        qf[kk] = *(const bf16x8*)(proj + (size_t)(b * SEQT + t0 + w * 16 + rl) * 1280
                                  + h * 64 + kk * 32 + g * 8);

    f32x4 oacc[4];
    #pragma unroll
    for (int n = 0; n < 4; ++n) oacc[n] = (f32x4){0.f, 0.f, 0.f, 0.f};
    float lpart[4] = {0.f, 0.f, 0.f, 0.f};

    for (int s0 = 0; s0 < SEQT; s0 += 64) {
        __syncthreads();
        #pragma unroll
        for (int cc = 0; cc < 2; ++cc) {
            int c = tid + cc * 256;
            int sr = c >> 3, hc = c & 7;
            // K rows (seq) from proj col 256
            u16x8 kv = *(const u16x8*)(proj + (size_t)(b * SEQT + s0 + sr) * 1280
                                       + 256 + h * 64 + hc * 8);
            *(u16x8*)&Ks[sr][hc * 8] = kv;
            // V^T rows (dim) from vT
            u16x8 vv = *(const u16x8*)(vT + (size_t)(h * 64 + sr) * BT
                                       + b * SEQT + s0 + hc * 8);
            *(u16x8*)&Vs[sr][hc * 8] = vv;
        }
        if (tid < 127) {
            int dd = s0 - t0 + 448 + tid;
            rb_s[tid] = rpb[dd * 4 + h];
        }
        __syncthreads();

        // S = Q K^T
        f32x4 sacc[4];
        #pragma unroll
        for (int n = 0; n < 4; ++n) sacc[n] = (f32x4){0.f, 0.f, 0.f, 0.f};
        #pragma unroll
        for (int kk = 0; kk < 2; ++kk) {
            #pragma unroll
            for (int n = 0; n < 4; ++n) {
                bf16x8 kf = *(const bf16x8*)&Ks[n * 16 + rl][kk * 32 + g * 8];
                sacc[n] = MFMA_BF16(qf[kk], kf, sacc[n]);
            }
        }

        // p = exp(s*scale + bias); accumulate row-sums; P -> LDS (wave-local rows)
        #pragma unroll
        for (int n = 0; n < 4; ++n) {
            #pragma unroll
            for (int r = 0; r < 4; ++r) {
                int relc = (n * 16 + rl) - (w * 16 + g * 4 + r) + 63;
                float p = __expf(sacc[n][r] * ASCALE + rb_s[relc]);
                lpart[r] += p;
                Ps[w * 16 + g * 4 + r][n * 16 + rl] = f2bf(p);
            }
        }

        // O += P V
        #pragma unroll
        for (int kk = 0; kk < 2; ++kk) {
            bf16x8 pf = *(const bf16x8*)&Ps[w * 16 + rl][kk * 32 + g * 8];
            #pragma unroll
            for (int n = 0; n < 4; ++n) {
                bf16x8 vf = *(const bf16x8*)&Vs[n * 16 + rl][kk * 32 + g * 8];
                oacc[n] = MFMA_BF16(pf, vf, oacc[n]);
            }
        }
    }

    // reduce row-sums over the 16-lane group (rows are per (g,r))
    #pragma unroll
    for (int r = 0; r < 4; ++r) {
        #pragma unroll
        for (int mk = 1; mk < 16; mk <<= 1) lpart[r] += __shfl_xor(lpart[r], mk);
    }
    const size_t obase = (size_t)b * SEQT * 256 + h * 64;
    #pragma unroll
    for (int n = 0; n < 4; ++n) {
        #pragma unroll
        for (int r = 0; r < 4; ++r) {
            float o = oacc[n][r] / lpart[r];
            gout[obase + (size_t)(t0 + w * 16 + g * 4 + r) * 256 + n * 16 + rl] = f2bf(o);
        }
    }
}

// ---------- local windowed attention: 1 wave per t; lq/lk/lv in proj (stride 1280) ----------
__global__ __launch_bounds__(256)
void local_attn(const unsigned short* __restrict__ proj,
                const float* __restrict__ lk_bias, const float* __restrict__ lv_bias,
                unsigned short* __restrict__ fused) {
    const int tid = threadIdx.x;
    const int wv = tid >> 6, lane = tid & 63;
    const int row = blockIdx.x * 4 + wv;
    const int b = row >> 9, tt = row & 511;

    ushort4 qv = *((const ushort4*)(proj + (size_t)row * 1280 + 512) + lane);
    float qf[4] = {bf2f(qv.x), bf2f(qv.y), bf2f(qv.z), bf2f(qv.w)};

    float sw[10];
    #pragma unroll
    for (int w = 0; w < 10; ++w) {
        int src = tt + w - 5;
        float kf[4];
        if (src >= 0 && src < 512) {
            ushort4 kv = *((const ushort4*)(proj + (size_t)(b * 512 + src) * 1280 + 768) + lane);
            kf[0] = bf2f(kv.x); kf[1] = bf2f(kv.y); kf[2] = bf2f(kv.z); kf[3] = bf2f(kv.w);
        } else {
            float4 kb4 = *((const float4*)lk_bias + lane);
            kf[0] = kb4.x; kf[1] = kb4.y; kf[2] = kb4.z; kf[3] = kb4.w;
        }
        float p = qf[0] * kf[0] + qf[1] * kf[1] + qf[2] * kf[2] + qf[3] * kf[3];
        #pragma unroll
        for (int mk = 1; mk < 64; mk <<= 1) p += __shfl_xor(p, mk);
        sw[w] = p * ASCALE;
    }
    float mx = sw[0];
    #pragma unroll
    for (int w = 1; w < 10; ++w) mx = fmaxf(mx, sw[w]);
    float pv[10], s = 0.f;
    #pragma unroll
    for (int w = 0; w < 10; ++w) { pv[w] = __expf(sw[w] - mx); s += pv[w]; }
    float inv = 1.f / s;

    float of[4] = {0.f, 0.f, 0.f, 0.f};
    #pragma unroll
    for (int w = 0; w < 10; ++w) {
        int src = tt + w - 5;
        float vf[4];
        if (src >= 0 && src < 512) {
            ushort4 vv = *((const ushort4*)(proj + (size_t)(b * 512 + src) * 1280 + 1024) + lane);
            vf[0] = bf2f(vv.x); vf[1] = bf2f(vv.y); vf[2] = bf2f(vv.z); vf[3] = bf2f(vv.w);
        } else {
            float4 vb4 = *((const float4*)lv_bias + lane);
            vf[0] = vb4.x; vf[1] = vb4.y; vf[2] = vb4.z; vf[3] = vb4.w;
        }
        float pw = pv[w] * inv;
        of[0] += pw * vf[0]; of[1] += pw * vf[1]; of[2] += pw * vf[2]; of[3] += pw * vf[3];
    }
    ushort4 o;
    o.x = f2bf(of[0]); o.y = f2bf(of[1]); o.z = f2bf(of[2]); o.w = f2bf(of[3]);
    *((ushort4*)(fused + (size_t)row * 512 + 256) + lane) = o;
}

// ---------- pooled mean over T (256 blocks, atomic accumulate) ----------
__global__ __launch_bounds__(256)
void pooled_mean2(const float* __restrict__ x, float* __restrict__ pooled) {
    int b = blockIdx.x >> 3, tc = blockIdx.x & 7;
    int d = threadIdx.x;
    const float* xp = x + ((size_t)b * SEQT + tc * 64) * 256 + d;
    float s = 0.f;
    #pragma unroll 8
    for (int t = 0; t < 64; ++t) s += xp[(size_t)t * 256];
    atomicAdd(&pooled[b * 256 + d], s * (1.0f / 512.0f));
}

// ---------- pattern scores (all fp32) ----------
__global__ __launch_bounds__(256)
void pattern_k(const float* __restrict__ pooled, const float* __restrict__ pe,
               const float* __restrict__ pq_w, const float* __restrict__ pq_b,
               const float* __restrict__ pk_w, const float* __restrict__ pk_b,
               float* __restrict__ out_scores) {
    __shared__ float pool_s[256];
    __shared__ float pes[3 * 256];
    __shared__ float pq_s[256];
    __shared__ float pk_s[3][256];
    __shared__ float pw_s[4][3];
    int b = blockIdx.x, d = threadIdx.x;
    pool_s[d] = pooled[b * 256 + d];
    pes[d] = pe[d]; pes[256 + d] = pe[256 + d]; pes[512 + d] = pe[512 + d];
    __syncthreads();
    float acc = pq_b[d];
    for (int k = 0; k < 256; ++k) acc += pool_s[k] * pq_w[k * 256 + d];
    pq_s[d] = acc;
    for (int j = 0; j < 3; ++j) {
        float a = pk_b[d];
        for (int k = 0; k < 256; ++k) a += pes[j * 256 + k] * pk_w[k * 256 + d];
        pk_s[j][d] = a;
    }
    __syncthreads();
    int h = d >> 6, lane = d & 63;
    float lg[3];
    #pragma unroll
    for (int j = 0; j < 3; ++j) {
        float p = pq_s[h * 64 + lane] * pk_s[j][h * 64 + lane];
        #pragma unroll
        for (int mk = 1; mk < 64; mk <<= 1) p += __shfl_xor(p, mk);
        lg[j] = p * ASCALE;
    }
    float mx = fmaxf(fmaxf(lg[0], lg[1]), lg[2]);
    float e0 = __expf(lg[0] - mx), e1 = __expf(lg[1] - mx), e2 = __expf(lg[2] - mx);
    float sinv = 1.f / (e0 + e1 + e2);
    if (lane == 0) { pw_s[h][0] = e0 * sinv; pw_s[h][1] = e1 * sinv; pw_s[h][2] = e2 * sinv; }
    __syncthreads();
    if (d < 3)
        out_scores[b * 3 + d] = 0.25f * (pw_s[0][d] + pw_s[1][d] + pw_s[2][d] + pw_s[3][d]);
}

extern "C" void kernel_launch(void* const* d_in, const int* in_sizes, int n_in,
                              void* d_out, int out_size, void* d_ws, size_t ws_size,
                              hipStream_t stream) {
    (void)in_sizes; (void)n_in; (void)out_size; (void)ws_size;
    const float* x    = (const float*)d_in[0];
    const float* gq_w = (const float*)d_in[1];  const float* gq_b = (const float*)d_in[2];
    const float* gk_w = (const float*)d_in[3];  const float* gk_b = (const float*)d_in[4];
    const float* gv_w = (const float*)d_in[5];  const float* gv_b = (const float*)d_in[6];
    const float* go_w = (const float*)d_in[7];  const float* go_b = (const float*)d_in[8];
    const float* rpb  = (const float*)d_in[9];
    const float* lq_w = (const float*)d_in[10]; const float* lq_b = (const float*)d_in[11];
    const float* lk_w = (const float*)d_in[12]; const float* lk_b = (const float*)d_in[13];
    const float* lv_w = (const float*)d_in[14]; const float* lv_b = (const float*)d_in[15];
    const float* pe   = (const float*)d_in[16];
    const float* pq_w = (const float*)d_in[17]; const float* pq_b = (const float*)d_in[18];
    const float* pk_w = (const float*)d_in[19]; const float* pk_b = (const float*)d_in[20];
    const float* f1_w = (const float*)d_in[21]; const float* f1_b = (const float*)d_in[22];
    const float* f2_w = (const float*)d_in[23]; const float* f2_b = (const float*)d_in[24];

    char* ws = (char*)d_ws;
    const size_t MB = 1024 * 1024;
    unsigned short* xb    = (unsigned short*)(ws + 0);        // [16384][256]; reused as g_out
    unsigned short* proj  = (unsigned short*)(ws + 8 * MB);   // [16384][1280]
    unsigned short* vT    = (unsigned short*)(ws + 48 * MB);  // [256][16384]
    unsigned short* fused = (unsigned short*)(ws + 56 * MB);  // [16384][512]
    unsigned short* hb    = (unsigned short*)(ws + 72 * MB);  // [16384][256]
    unsigned short* wts   = (unsigned short*)(ws + 80 * MB);
    unsigned short* gv_t  = wts;                 // [256][256]
    unsigned short* go_t  = gv_t + 65536;        // [256][256]
    unsigned short* f1_t  = go_t + 65536;        // [256][512]
    unsigned short* f2_t  = f1_t + 131072;       // [256][256]
    unsigned short* wcat  = f2_t + 65536;        // [1280][256]
    float* bcat   = (float*)(ws + 82 * MB);      // [1280]
    float* pooled = (float*)(ws + 83 * MB);      // [32][256]

    float* out = (float*)d_out;
    float* out_scores = out + (size_t)BT * 256;

    // 1. casts / weight transposes
    cast_x_kernel<<<4096, 256, 0, stream>>>(x, xb, BT * 256);
    wconv_kernel<<<256, 256, 0, stream>>>(gq_w, wcat + 0 * 65536, 256);
    wconv_kernel<<<256, 256, 0, stream>>>(gk_w, wcat + 1 * 65536, 256);
    wconv_kernel<<<256, 256, 0, stream>>>(lq_w, wcat + 2 * 65536, 256);
    wconv_kernel<<<256, 256, 0, stream>>>(lk_w, wcat + 3 * 65536, 256);
    wconv_kernel<<<256, 256, 0, stream>>>(lv_w, wcat + 4 * 65536, 256);
    wconv_kernel<<<256, 256, 0, stream>>>(gv_w, gv_t, 256);
    wconv_kernel<<<256, 256, 0, stream>>>(go_w, go_t, 256);
    wconv_kernel<<<512, 256, 0, stream>>>(f1_w, f1_t, 512);
    wconv_kernel<<<256, 256, 0, stream>>>(f2_w, f2_t, 256);
    biascat_kernel<<<5, 256, 0, stream>>>(gq_b, gk_b, lq_b, lk_b, lv_b, bcat);

    // 2. fused projection GEMM: [16384 x 256] x [1280 x 256]^T -> proj
    gemm128<<<dim3(BT / 128, 10), 256, 0, stream>>>(xb, wcat, bcat, 256, proj, 1280, 0, 0, 0, nullptr);
    // 2b. V projection, output-transposed: vT[d][t]
    gemm128<<<dim3(2, BT / 128), 256, 0, stream>>>(gv_t, xb, gv_b, 256, vT, BT, 0, 0, 1, nullptr);

    // 3. global attention -> g_out (reuses xb)
    attn_global2<<<dim3(SEQT / 64, NB * 4), 256, 0, stream>>>(proj, vT, rpb, xb);

    // 4. output proj into fused[:, 0:256]
    gemm128<<<dim3(BT / 128, 2), 256, 0, stream>>>(xb, go_t, go_b, 256, fused, 512, 0, 0, 0, nullptr);

    // 5. local attention into fused[:, 256:512]
    local_attn<<<BT / 4, 256, 0, stream>>>(proj, lk_b, lv_b, fused);

    // 6. FFN
    gemm128<<<dim3(BT / 128, 2), 256, 0, stream>>>(fused, f1_t, f1_b, 512, hb, 256, 0, 1, 0, nullptr);
    gemm128<<<dim3(BT / 128, 2), 256, 0, stream>>>(hb, f2_t, f2_b, 256, out, 256, 1, 0, 0, x);

    // 7. pattern path
    hipMemsetAsync(pooled, 0, 32 * 256 * sizeof(float), stream);
    pooled_mean2<<<256, 256, 0, stream>>>(x, pooled);
    pattern_k<<<NB, 256, 0, stream>>>(pooled, pe, pq_w, pq_b, pk_w, pk_b, out_scores);
}

// Round 3
// 299.726 us; speedup vs baseline: 1.1861x; 1.1861x over previous
//
#include <hip/hip_runtime.h>
#include <hip/hip_bf16.h>

typedef __attribute__((ext_vector_type(8))) __bf16 bf16x8;
typedef __attribute__((ext_vector_type(8))) unsigned short u16x8;
typedef __attribute__((ext_vector_type(4))) float f32x4;

#define MFMA_BF16(a,b,c) __builtin_amdgcn_mfma_f32_16x16x32_bf16((a),(b),(c),0,0,0)

#define ASCALE 0.125f
#define SEQT 512
#define NB 32
#define BT 16384  // NB*SEQT

#define GLD_LDS16(g, l) __builtin_amdgcn_global_load_lds( \
    (__attribute__((address_space(1))) void*)(g), \
    (__attribute__((address_space(3))) void*)(l), 16, 0, 0)

__device__ __forceinline__ unsigned short f2bf(float f) {
    unsigned int u = __float_as_uint(f);
    u += 0x7fffu + ((u >> 16) & 1u);
    return (unsigned short)(u >> 16);
}
__device__ __forceinline__ float bf2f(unsigned short h) {
    return __uint_as_float(((unsigned int)h) << 16);
}

// ---------- cast x (fp32 -> bf16) ----------
__global__ __launch_bounds__(256) void cast_x_kernel(const float* __restrict__ x,
                                                     unsigned short* __restrict__ xb, int n) {
    int i = (blockIdx.x * 256 + threadIdx.x) * 4;
    if (i < n) {
        float4 v = *(const float4*)(x + i);
        ushort4 o;
        o.x = f2bf(v.x); o.y = f2bf(v.y); o.z = f2bf(v.z); o.w = f2bf(v.w);
        *(ushort4*)(xb + i) = o;
    }
}

// ---------- fused weight transpose+cast for all 9 weights + 5-bias concat ----------
struct WPack {
    const float* src[9];
    unsigned short* dst[9];
    int K[9];
    const float* bsrc[5];
    float* bdst;
};

__global__ __launch_bounds__(256) void wconv_all(WPack p) {
    const int z = blockIdx.z;
    const int tid = threadIdx.x;
    if (z == 9) {
        int idx = blockIdx.y * 8 + blockIdx.x;
        if (idx < 5) p.bdst[idx * 256 + tid] = p.bsrc[idx][tid];
        return;
    }
    const int K = p.K[z];
    const int k0 = blockIdx.x * 64;
    if (k0 >= K) return;
    const int n0 = blockIdx.y * 64;
    __shared__ float tile[64][65];
    const int tx = tid & 63, ty = tid >> 6;
    const float* src = p.src[z];
    #pragma unroll
    for (int i = 0; i < 16; ++i) {
        int r = ty * 16 + i;
        tile[r][tx] = src[(size_t)(k0 + r) * 256 + n0 + tx];
    }
    __syncthreads();
    unsigned short* dst = p.dst[z];
    #pragma unroll
    for (int i = 0; i < 16; ++i) {
        int r = ty * 16 + i;
        dst[(size_t)(n0 + r) * K + k0 + tx] = f2bf(tile[tx][r]);
    }
}

// ---------- GEMM, 128xBN tile, double-buffered LDS (2-phase), BK=32 ----------
// C[m][n] = sum_k A[m][k]*Bt[n][k] + bias. mode 0: bf16 out; 1: f32 out (+resid).
template<int BN>
__global__ __launch_bounds__(256)
void gemm_db(const unsigned short* __restrict__ A, const unsigned short* __restrict__ Bt,
             const float* __restrict__ bias, int K,
             void* __restrict__ out, int ldc, int mode, int do_relu, int bias_row,
             const float* __restrict__ resid) {
    constexpr int BM = 128;
    constexpr int MF = (BN == 128) ? 4 : 2;
    constexpr int AR = (BM * 32) / 2048;
    constexpr int BR = (BN * 32) / 2048;
    __shared__ __align__(16) unsigned short As[2][BM * 32];
    __shared__ __align__(16) unsigned short Bs[2][BN * 32];
    const int tid = threadIdx.x;
    const int w = tid >> 6, l = tid & 63, g = l >> 4, rl = l & 15;
    const int wrow = (BN == 128) ? (w >> 1) * 64 : w * 32;
    const int wcol = (BN == 128) ? (w & 1) * 64 : 0;
    const int m0 = blockIdx.x * BM, n0 = blockIdx.y * BN;

    f32x4 acc[MF][4];
    #pragma unroll
    for (int m = 0; m < MF; ++m)
        #pragma unroll
        for (int n = 0; n < 4; ++n) acc[m][n] = (f32x4){0.f, 0.f, 0.f, 0.f};

    auto stage = [&](int buf, int k0) {
        #pragma unroll
        for (int j = 0; j < AR; ++j) {
            int e = j * 256 + tid;
            GLD_LDS16(A + (size_t)(m0 + (e >> 2)) * K + k0 + (e & 3) * 8, &As[buf][e * 8]);
        }
        #pragma unroll
        for (int j = 0; j < BR; ++j) {
            int e = j * 256 + tid;
            GLD_LDS16(Bt + (size_t)(n0 + (e >> 2)) * K + k0 + (e & 3) * 8, &Bs[buf][e * 8]);
        }
    };

    const int NIT = K >> 5;
    stage(0, 0);
    __syncthreads();
    for (int it = 0; it < NIT; ++it) {
        const int cur = it & 1;
        if (it + 1 < NIT) stage(cur ^ 1, (it + 1) * 32);
        bf16x8 af[MF], bfr[4];
        #pragma unroll
        for (int m = 0; m < MF; ++m)
            af[m] = *(const bf16x8*)&As[cur][(wrow + m * 16 + rl) * 32 + g * 8];
        #pragma unroll
        for (int n = 0; n < 4; ++n)
            bfr[n] = *(const bf16x8*)&Bs[cur][(wcol + n * 16 + rl) * 32 + g * 8];
        #pragma unroll
        for (int m = 0; m < MF; ++m)
            #pragma unroll
            for (int n = 0; n < 4; ++n)
                acc[m][n] = MFMA_BF16(af[m], bfr[n], acc[m][n]);
        __syncthreads();
    }

    #pragma unroll
    for (int m = 0; m < MF; ++m) {
        #pragma unroll
        for (int n = 0; n < 4; ++n) {
            #pragma unroll
            for (int r = 0; r < 4; ++r) {
                int row = m0 + wrow + m * 16 + g * 4 + r;
                int col = n0 + wcol + n * 16 + rl;
                float v = acc[m][n][r] + (bias_row ? bias[row] : bias[col]);
                if (do_relu) v = fmaxf(v, 0.f);
                if (mode == 0) {
                    ((unsigned short*)out)[(size_t)row * ldc + col] = f2bf(v);
                } else {
                    float res = resid ? resid[(size_t)row * ldc + col] : 0.f;
                    ((float*)out)[(size_t)row * ldc + col] = v + res;
                }
            }
        }
    }
}

// ---------- global attention: no online-max (logits bounded), V pre-transposed ----------
__global__ __launch_bounds__(256)
void attn_global2(const unsigned short* __restrict__ proj, const unsigned short* __restrict__ vT,
                  const float* __restrict__ rpb, unsigned short* __restrict__ gout) {
    __shared__ __align__(16) unsigned short Ks[64][72];
    __shared__ __align__(16) unsigned short Vs[64][72];
    __shared__ __align__(16) unsigned short Ps[64][72];
    __shared__ float rb_s[127];

    const int tid = threadIdx.x;
    const int w = tid >> 6, l = tid & 63, g = l >> 4, rl = l & 15;
    const int bh = blockIdx.y, b = bh >> 2, h = bh & 3;
    const int t0 = blockIdx.x * 64;

    bf16x8 qf[2];
    #pragma unroll
    for (int kk = 0; kk < 2; ++kk)
        qf[kk] = *(const bf16x8*)(proj + (size_t)(b * SEQT + t0 + w * 16 + rl) * 1280
                                  + h * 64 + kk * 32 + g * 8);

    f32x4 oacc[4];
    #pragma unroll
    for (int n = 0; n < 4; ++n) oacc[n] = (f32x4){0.f, 0.f, 0.f, 0.f};
    float lpart[4] = {0.f, 0.f, 0.f, 0.f};

    for (int s0 = 0; s0 < SEQT; s0 += 64) {
        __syncthreads();
        #pragma unroll
        for (int cc = 0; cc < 2; ++cc) {
            int c = tid + cc * 256;
            int sr = c >> 3, hc = c & 7;
            u16x8 kv = *(const u16x8*)(proj + (size_t)(b * SEQT + s0 + sr) * 1280
                                       + 256 + h * 64 + hc * 8);
            *(u16x8*)&Ks[sr][hc * 8] = kv;
            u16x8 vv = *(const u16x8*)(vT + (size_t)(h * 64 + sr) * BT
                                       + b * SEQT + s0 + hc * 8);
            *(u16x8*)&Vs[sr][hc * 8] = vv;
        }
        if (tid < 127) {
            int dd = s0 - t0 + 448 + tid;
            rb_s[tid] = rpb[dd * 4 + h];
        }
        __syncthreads();

        f32x4 sacc[4];
        #pragma unroll
        for (int n = 0; n < 4; ++n) sacc[n] = (f32x4){0.f, 0.f, 0.f, 0.f};
        #pragma unroll
        for (int kk = 0; kk < 2; ++kk) {
            #pragma unroll
            for (int n = 0; n < 4; ++n) {
                bf16x8 kf = *(const bf16x8*)&Ks[n * 16 + rl][kk * 32 + g * 8];
                sacc[n] = MFMA_BF16(qf[kk], kf, sacc[n]);
            }
        }

        #pragma unroll
        for (int n = 0; n < 4; ++n) {
            #pragma unroll
            for (int r = 0; r < 4; ++r) {
                int relc = (n * 16 + rl) - (w * 16 + g * 4 + r) + 63;
                float p = __expf(sacc[n][r] * ASCALE + rb_s[relc]);
                lpart[r] += p;
                Ps[w * 16 + g * 4 + r][n * 16 + rl] = f2bf(p);
            }
        }

        #pragma unroll
        for (int kk = 0; kk < 2; ++kk) {
            bf16x8 pf = *(const bf16x8*)&Ps[w * 16 + rl][kk * 32 + g * 8];
            #pragma unroll
            for (int n = 0; n < 4; ++n) {
                bf16x8 vf = *(const bf16x8*)&Vs[n * 16 + rl][kk * 32 + g * 8];
                oacc[n] = MFMA_BF16(pf, vf, oacc[n]);
            }
        }
    }

    #pragma unroll
    for (int r = 0; r < 4; ++r) {
        #pragma unroll
        for (int mk = 1; mk < 16; mk <<= 1) lpart[r] += __shfl_xor(lpart[r], mk);
    }
    const size_t obase = (size_t)b * SEQT * 256 + h * 64;
    #pragma unroll
    for (int n = 0; n < 4; ++n) {
        #pragma unroll
        for (int r = 0; r < 4; ++r) {
            float o = oacc[n][r] / lpart[r];
            gout[obase + (size_t)(t0 + w * 16 + g * 4 + r) * 256 + n * 16 + rl] = f2bf(o);
        }
    }
}

// ---------- local windowed attention ----------
__global__ __launch_bounds__(256)
void local_attn(const unsigned short* __restrict__ proj,
                const float* __restrict__ lk_bias, const float* __restrict__ lv_bias,
                unsigned short* __restrict__ fused) {
    const int tid = threadIdx.x;
    const int wv = tid >> 6, lane = tid & 63;
    const int row = blockIdx.x * 4 + wv;
    const int b = row >> 9, tt = row & 511;

    ushort4 qv = *((const ushort4*)(proj + (size_t)row * 1280 + 512) + lane);
    float qf[4] = {bf2f(qv.x), bf2f(qv.y), bf2f(qv.z), bf2f(qv.w)};

    float sw[10];
    #pragma unroll
    for (int w = 0; w < 10; ++w) {
        int src = tt + w - 5;
        float kf[4];
        if (src >= 0 && src < 512) {
            ushort4 kv = *((const ushort4*)(proj + (size_t)(b * 512 + src) * 1280 + 768) + lane);
            kf[0] = bf2f(kv.x); kf[1] = bf2f(kv.y); kf[2] = bf2f(kv.z); kf[3] = bf2f(kv.w);
        } else {
            float4 kb4 = *((const float4*)lk_bias + lane);
            kf[0] = kb4.x; kf[1] = kb4.y; kf[2] = kb4.z; kf[3] = kb4.w;
        }
        float p = qf[0] * kf[0] + qf[1] * kf[1] + qf[2] * kf[2] + qf[3] * kf[3];
        #pragma unroll
        for (int mk = 1; mk < 64; mk <<= 1) p += __shfl_xor(p, mk);
        sw[w] = p * ASCALE;
    }
    float mx = sw[0];
    #pragma unroll
    for (int w = 1; w < 10; ++w) mx = fmaxf(mx, sw[w]);
    float pv[10], s = 0.f;
    #pragma unroll
    for (int w = 0; w < 10; ++w) { pv[w] = __expf(sw[w] - mx); s += pv[w]; }
    float inv = 1.f / s;

    float of[4] = {0.f, 0.f, 0.f, 0.f};
    #pragma unroll
    for (int w = 0; w < 10; ++w) {
        int src = tt + w - 5;
        float vf[4];
        if (src >= 0 && src < 512) {
            ushort4 vv = *((const ushort4*)(proj + (size_t)(b * 512 + src) * 1280 + 1024) + lane);
            vf[0] = bf2f(vv.x); vf[1] = bf2f(vv.y); vf[2] = bf2f(vv.z); vf[3] = bf2f(vv.w);
        } else {
            float4 vb4 = *((const float4*)lv_bias + lane);
            vf[0] = vb4.x; vf[1] = vb4.y; vf[2] = vb4.z; vf[3] = vb4.w;
        }
        float pw = pv[w] * inv;
        of[0] += pw * vf[0]; of[1] += pw * vf[1]; of[2] += pw * vf[2]; of[3] += pw * vf[3];
    }
    ushort4 o;
    o.x = f2bf(of[0]); o.y = f2bf(of[1]); o.z = f2bf(of[2]); o.w = f2bf(of[3]);
    *((ushort4*)(fused + (size_t)row * 512 + 256) + lane) = o;
}

// ---------- pooled mean partials (no atomics) ----------
__global__ __launch_bounds__(256)
void pooled_part(const unsigned short* __restrict__ xb, float* __restrict__ pp) {
    int b = blockIdx.x >> 3, tc = blockIdx.x & 7;
    int d = threadIdx.x;
    const unsigned short* xp = xb + ((size_t)b * SEQT + tc * 64) * 256 + d;
    float s = 0.f;
    #pragma unroll 8
    for (int t = 0; t < 64; ++t) s += bf2f(xp[(size_t)t * 256]);
    pp[(size_t)(tc * 32 + b) * 256 + d] = s * (1.0f / 512.0f);
}

// ---------- pattern scores ----------
__global__ __launch_bounds__(256)
void pattern_k(const float* __restrict__ pp, const float* __restrict__ pe,
               const float* __restrict__ pq_w, const float* __restrict__ pq_b,
               const float* __restrict__ pk_w, const float* __restrict__ pk_b,
               float* __restrict__ out_scores) {
    __shared__ float pool_s[256];
    __shared__ float pes[3 * 256];
    __shared__ float pq_s[256];
    __shared__ float pk_s[3][256];
    __shared__ float pw_s[4][3];
    int b = blockIdx.x, d = threadIdx.x;
    float ps = 0.f;
    #pragma unroll
    for (int tc = 0; tc < 8; ++tc) ps += pp[(size_t)(tc * 32 + b) * 256 + d];
    pool_s[d] = ps;
    pes[d] = pe[d]; pes[256 + d] = pe[256 + d]; pes[512 + d] = pe[512 + d];
    __syncthreads();
    float acc = pq_b[d];
    for (int k = 0; k < 256; ++k) acc += pool_s[k] * pq_w[k * 256 + d];
    pq_s[d] = acc;
    for (int j = 0; j < 3; ++j) {
        float a = pk_b[d];
        for (int k = 0; k < 256; ++k) a += pes[j * 256 + k] * pk_w[k * 256 + d];
        pk_s[j][d] = a;
    }
    __syncthreads();
    int h = d >> 6, lane = d & 63;
    float lg[3];
    #pragma unroll
    for (int j = 0; j < 3; ++j) {
        float p = pq_s[h * 64 + lane] * pk_s[j][h * 64 + lane];
        #pragma unroll
        for (int mk = 1; mk < 64; mk <<= 1) p += __shfl_xor(p, mk);
        lg[j] = p * ASCALE;
    }
    float mx = fmaxf(fmaxf(lg[0], lg[1]), lg[2]);
    float e0 = __expf(lg[0] - mx), e1 = __expf(lg[1] - mx), e2 = __expf(lg[2] - mx);
    float sinv = 1.f / (e0 + e1 + e2);
    if (lane == 0) { pw_s[h][0] = e0 * sinv; pw_s[h][1] = e1 * sinv; pw_s[h][2] = e2 * sinv; }
    __syncthreads();
    if (d < 3)
        out_scores[b * 3 + d] = 0.25f * (pw_s[0][d] + pw_s[1][d] + pw_s[2][d] + pw_s[3][d]);
}

extern "C" void kernel_launch(void* const* d_in, const int* in_sizes, int n_in,
                              void* d_out, int out_size, void* d_ws, size_t ws_size,
                              hipStream_t stream) {
    (void)in_sizes; (void)n_in; (void)out_size; (void)ws_size;
    const float* x    = (const float*)d_in[0];
    const float* gq_w = (const float*)d_in[1];  const float* gq_b = (const float*)d_in[2];
    const float* gk_w = (const float*)d_in[3];  const float* gk_b = (const float*)d_in[4];
    const float* gv_w = (const float*)d_in[5];  const float* gv_b = (const float*)d_in[6];
    const float* go_w = (const float*)d_in[7];  const float* go_b = (const float*)d_in[8];
    const float* rpb  = (const float*)d_in[9];
    const float* lq_w = (const float*)d_in[10]; const float* lq_b = (const float*)d_in[11];
    const float* lk_w = (const float*)d_in[12]; const float* lk_b = (const float*)d_in[13];
    const float* lv_w = (const float*)d_in[14]; const float* lv_b = (const float*)d_in[15];
    const float* pe   = (const float*)d_in[16];
    const float* pq_w = (const float*)d_in[17]; const float* pq_b = (const float*)d_in[18];
    const float* pk_w = (const float*)d_in[19]; const float* pk_b = (const float*)d_in[20];
    const float* f1_w = (const float*)d_in[21]; const float* f1_b = (const float*)d_in[22];
    const float* f2_w = (const float*)d_in[23]; const float* f2_b = (const float*)d_in[24];

    char* ws = (char*)d_ws;
    const size_t MB = 1024 * 1024;
    unsigned short* xb    = (unsigned short*)(ws + 0);        // [16384][256]; reused as g_out
    unsigned short* proj  = (unsigned short*)(ws + 8 * MB);   // [16384][1280]
    unsigned short* vT    = (unsigned short*)(ws + 48 * MB);  // [256][16384]
    unsigned short* fused = (unsigned short*)(ws + 56 * MB);  // [16384][512]
    unsigned short* hb    = (unsigned short*)(ws + 72 * MB);  // [16384][256]
    unsigned short* wts   = (unsigned short*)(ws + 80 * MB);
    unsigned short* gv_t  = wts;                 // [256][256]
    unsigned short* go_t  = gv_t + 65536;        // [256][256]
    unsigned short* f1_t  = go_t + 65536;        // [256][512]
    unsigned short* f2_t  = f1_t + 131072;       // [256][256]
    unsigned short* wcat  = f2_t + 65536;        // [1280][256]
    float* bcat = (float*)(ws + 82 * MB);        // [1280]
    float* pp   = (float*)(ws + 83 * MB);        // [8*32][256] partials

    float* out = (float*)d_out;
    float* out_scores = out + (size_t)BT * 256;

    // 1. cast x, all weight transposes in one launch
    cast_x_kernel<<<4096, 256, 0, stream>>>(x, xb, BT * 256);
    WPack p;
    p.src[0] = gq_w; p.dst[0] = wcat + 0 * 65536; p.K[0] = 256;
    p.src[1] = gk_w; p.dst[1] = wcat + 1 * 65536; p.K[1] = 256;
    p.src[2] = lq_w; p.dst[2] = wcat + 2 * 65536; p.K[2] = 256;
    p.src[3] = lk_w; p.dst[3] = wcat + 3 * 65536; p.K[3] = 256;
    p.src[4] = lv_w; p.dst[4] = wcat + 4 * 65536; p.K[4] = 256;
    p.src[5] = gv_w; p.dst[5] = gv_t;  p.K[5] = 256;
    p.src[6] = go_w; p.dst[6] = go_t;  p.K[6] = 256;
    p.src[7] = f1_w; p.dst[7] = f1_t;  p.K[7] = 512;
    p.src[8] = f2_w; p.dst[8] = f2_t;  p.K[8] = 256;
    p.bsrc[0] = gq_b; p.bsrc[1] = gk_b; p.bsrc[2] = lq_b; p.bsrc[3] = lk_b; p.bsrc[4] = lv_b;
    p.bdst = bcat;
    wconv_all<<<dim3(8, 4, 10), 256, 0, stream>>>(p);
    pooled_part<<<256, 256, 0, stream>>>(xb, pp);

    // 2. fused projection GEMM (q|k|lq|lk|lv) + V^T projection
    gemm_db<128><<<dim3(BT / 128, 10), 256, 0, stream>>>(xb, wcat, bcat, 256, proj, 1280, 0, 0, 0, nullptr);
    gemm_db<64><<<dim3(2, BT / 64), 256, 0, stream>>>(gv_t, xb, gv_b, 256, vT, BT, 0, 0, 1, nullptr);

    // 3. global attention -> g_out (reuses xb)
    attn_global2<<<dim3(SEQT / 64, NB * 4), 256, 0, stream>>>(proj, vT, rpb, xb);

    // 4. output proj into fused[:, 0:256]
    gemm_db<64><<<dim3(BT / 128, 4), 256, 0, stream>>>(xb, go_t, go_b, 256, fused, 512, 0, 0, 0, nullptr);

    // 5. local attention into fused[:, 256:512]
    local_attn<<<BT / 4, 256, 0, stream>>>(proj, lk_b, lv_b, fused);

    // 6. FFN
    gemm_db<64><<<dim3(BT / 128, 4), 256, 0, stream>>>(fused, f1_t, f1_b, 512, hb, 256, 0, 1, 0, nullptr);
    gemm_db<64><<<dim3(BT / 128, 4), 256, 0, stream>>>(hb, f2_t, f2_b, 256, out, 256, 1, 0, 0, x);

    // 7. pattern path
    pattern_k<<<NB, 256, 0, stream>>>(pp, pe, pq_w, pq_b, pk_w, pk_b, out_scores);
}